// Round 12
// baseline (167.569 us; speedup 1.0000x reference)
//
#include <hip/hip_runtime.h>
#include <math.h>

#define N_EMBD 768
#define N_HEAD 12
#define HEAD_DIM 64
#define SEQ 2048
#define BATCH 2

typedef __attribute__((ext_vector_type(8))) short v8s;   // 8 bf16 (4 VGPRs)
typedef __attribute__((ext_vector_type(4))) float v4f;   // 4 fp32

__device__ __forceinline__ unsigned short f2bf(float f) {
    union { float f; unsigned int u; } x; x.f = f;
    unsigned int u = x.u + 0x7fffu + ((x.u >> 16) & 1u);
    return (unsigned short)(u >> 16);
}
__device__ __forceinline__ float bf2f(unsigned short s) {
    union { unsigned int u; float f; } x; x.u = ((unsigned int)s) << 16;
    return x.f;
}
// pack two fp32 -> packed bf16 pair (round-half-up via +0x8000, then byte-perm)
__device__ __forceinline__ unsigned int pack_bf16(float lo, float hi) {
    unsigned int ul = __float_as_uint(lo) + 0x8000u;
    unsigned int uh = __float_as_uint(hi) + 0x8000u;
    return __builtin_amdgcn_perm(uh, ul, 0x07060302);  // {hi[3],hi[2],lo[3],lo[2]}
}

__device__ __forceinline__ void gload_lds16(const unsigned short* g, unsigned short* l) {
    __builtin_amdgcn_global_load_lds(
        (const __attribute__((address_space(1))) void*)g,
        (__attribute__((address_space(3))) void*)l, 16, 0, 0);
}

// Q pre-scale: 1/sqrt(64) * log2(e)
#define QSCALE 0.1803368801111396f

// ---------------------------------------------------------------------------
// Prep: cast x -> bf16 (blocks [0,1536)), transpose+cast W_attn (1536..3264),
// transpose+cast W_proj (3264..3840).
// ---------------------------------------------------------------------------
__global__ __launch_bounds__(256) void prep_kernel(
    const float* __restrict__ x,
    const float* __restrict__ W_attn,
    const float* __restrict__ W_proj,
    unsigned short* __restrict__ xb,
    unsigned short* __restrict__ wta,
    unsigned short* __restrict__ wtp)
{
    __shared__ float t[32][33];
    const int blk = (int)blockIdx.x;
    if (blk < 1536) {
        const int i = (blk * 256 + threadIdx.x) * 8;
        const float4 a = *(const float4*)(x + i);
        const float4 b = *(const float4*)(x + i + 4);
        ushort4 s0, s1;
        s0.x = f2bf(a.x); s0.y = f2bf(a.y); s0.z = f2bf(a.z); s0.w = f2bf(a.w);
        s1.x = f2bf(b.x); s1.y = f2bf(b.y); s1.z = f2bf(b.z); s1.w = f2bf(b.w);
        *(ushort4*)(xb + i) = s0;
        *(ushort4*)(xb + i + 4) = s1;
        return;
    }
    const float* in; unsigned short* out; int R, C, bx, by;
    if (blk < 1536 + 1728) {
        const int b2 = blk - 1536;
        in = W_attn; out = wta; R = 768; C = 2304;
        bx = (b2 % 72) * 32; by = (b2 / 72) * 32;
    } else {
        const int b2 = blk - 3264;
        in = W_proj; out = wtp; R = 768; C = 768;
        bx = (b2 % 24) * 32; by = (b2 / 24) * 32;
    }
    const int tx = threadIdx.x & 31, ty = threadIdx.x >> 5;
#pragma unroll
    for (int i = 0; i < 32; i += 8)
        t[ty + i][tx] = in[(size_t)(by + ty + i) * C + bx + tx];
    __syncthreads();
#pragma unroll
    for (int i = 0; i < 32; i += 8)
        out[(size_t)(bx + ty + i) * R + by + tx] = f2bf(t[tx][ty + i]);
}

// ---------------------------------------------------------------------------
// Kernel 1: QKV GEMM, bf16 MFMA, 128x128 tile, BK=64 (12 iterations, half the
// barriers of BK=32), double-buffered DMA staging with chunk-XOR swizzle
// ([row][64] layout has 128B row stride = full bank alias without it).
// ---------------------------------------------------------------------------
__global__ __launch_bounds__(256) void qkv_gemm_mfma(
    const unsigned short* __restrict__ A,    // bf16 [4096][768]
    const unsigned short* __restrict__ Bt,   // bf16 [2304][768]
    const float* __restrict__ bias,
    unsigned short* __restrict__ qg,
    unsigned short* __restrict__ kg,
    unsigned short* __restrict__ vg)
{
    __shared__ __align__(16) unsigned short as[2][128 * 64];  // 16KB each buf
    __shared__ __align__(16) unsigned short bs[2][128 * 64];
    const int K = 768;
    const int tid = threadIdx.x;
    const int lane = tid & 63;
    const int w = tid >> 6;
    const int wm = w >> 1, wn = w & 1;
    const int quad = lane >> 4, c = lane & 15;
    const int bm = blockIdx.y * 128;
    const int bn = blockIdx.x * 128;

    // staging: 1024 16B-chunks per operand per stage; 4 per thread.
    // thread (r0 = tid>>3, kc = tid&7) loads global chunk (kc ^ (r0&7)) so
    // LDS[row][kc] = global[row][kc ^ (row&7)]  (rows r0+32p share r0&7).
    const int r0 = tid >> 3;
    const int kosw = ((tid & 7) ^ (r0 & 7)) * 8;
    const unsigned short* ap = A  + (size_t)(bm + r0) * K + kosw;
    const unsigned short* bp = Bt + (size_t)(bn + r0) * K + kosw;

    v4f acc[4][4];
#pragma unroll
    for (int i = 0; i < 4; i++)
#pragma unroll
        for (int j = 0; j < 4; j++) acc[i][j] = (v4f){0.f, 0.f, 0.f, 0.f};

    // prologue: stage k0=0 into buf 0
#pragma unroll
    for (int p = 0; p < 4; p++) {
        gload_lds16(ap + (size_t)p * 32 * K, &as[0][(tid + p * 256) * 8]);
        gload_lds16(bp + (size_t)p * 32 * K, &bs[0][(tid + p * 256) * 8]);
    }

    int bufi = 0;
    for (int k0 = 0; k0 < K; k0 += 64, bufi ^= 1) {
        __syncthreads();   // drains DMA(k0) into buf[bufi]; prev reads done
        if (k0 + 64 < K) {
            const int kn = k0 + 64;
#pragma unroll
            for (int p = 0; p < 4; p++) {
                gload_lds16(ap + kn + (size_t)p * 32 * K, &as[bufi ^ 1][(tid + p * 256) * 8]);
                gload_lds16(bp + kn + (size_t)p * 32 * K, &bs[bufi ^ 1][(tid + p * 256) * 8]);
            }
        }

#pragma unroll
        for (int kh = 0; kh < 2; kh++) {
            v8s af[4], bf[4];
#pragma unroll
            for (int fm = 0; fm < 4; fm++) {
                const int row = wm * 64 + fm * 16 + c;
                const int swz = ((kh * 4 + quad) ^ (c & 7)) * 8;
                af[fm] = *(const v8s*)&as[bufi][row * 64 + swz];
            }
#pragma unroll
            for (int fn = 0; fn < 4; fn++) {
                const int row = wn * 64 + fn * 16 + c;
                const int swz = ((kh * 4 + quad) ^ (c & 7)) * 8;
                bf[fn] = *(const v8s*)&bs[bufi][row * 64 + swz];
            }
#pragma unroll
            for (int fm = 0; fm < 4; fm++)
#pragma unroll
                for (int fn = 0; fn < 4; fn++)
                    acc[fm][fn] = __builtin_amdgcn_mfma_f32_16x16x32_bf16(af[fm], bf[fn], acc[fm][fn], 0, 0, 0);
        }
    }

    const int which = bn / N_EMBD;
    const int rem_base = bn - which * N_EMBD;
#pragma unroll
    for (int fm = 0; fm < 4; fm++) {
        const int m0 = bm + wm * 64 + fm * 16 + quad * 4;
        const int b = m0 >> 11;
        const int t0 = m0 & (SEQ - 1);
#pragma unroll
        for (int fn = 0; fn < 4; fn++) {
            const int rem = rem_base + wn * 64 + fn * 16 + c;
            const int h = rem >> 6, d = rem & 63;
            const float bv = bias[bn + wn * 64 + fn * 16 + c];
            const size_t bh = (size_t)(b * N_HEAD + h);
            if (which == 2) {
                ushort4 o;
                o.x = f2bf(acc[fm][fn][0] + bv);
                o.y = f2bf(acc[fm][fn][1] + bv);
                o.z = f2bf(acc[fm][fn][2] + bv);
                o.w = f2bf(acc[fm][fn][3] + bv);
                *(ushort4*)(vg + (bh * 64 + d) * SEQ + t0) = o;
            } else {
                unsigned short* dst = (which == 0) ? qg : kg;
                const float sc = (which == 0) ? QSCALE : 1.0f;
#pragma unroll
                for (int r = 0; r < 4; r++)
                    dst[(bh * SEQ + t0 + r) * 64 + d] = f2bf((acc[fm][fn][r] + bv) * sc);
            }
        }
    }
}

// ---------------------------------------------------------------------------
// Kernel 2: causal flash attention (R8 structure: 64 q/block, 16 q/wave,
// split-K, fixed-max softmax, S^T operands, swizzled DMA staging, dbuf).
// Single-chunk rows (c2 < 8) normalize in-register and write y directly.
// ---------------------------------------------------------------------------
__global__ __launch_bounds__(256) void attn_kernel(
    const unsigned short* __restrict__ qg,
    const unsigned short* __restrict__ kg,
    const unsigned short* __restrict__ vg,
    unsigned short* __restrict__ pO,   // [bh*80+c2][64][64] bf16, unnormalized
    float* __restrict__ pl,            // [bh*80+c2][64] row sums
    unsigned short* __restrict__ y)    // bf16 [B,T,C] (direct path)
{
    __shared__ __align__(16) unsigned short ks[2][64 * 64];
    __shared__ __align__(16) unsigned short vs[2][64 * 64];
    __shared__ __align__(16) unsigned short ps[4][16 * 64];

    const int tid  = threadIdx.x;
    const int w    = tid >> 6;
    const int lane = tid & 63;
    const int quad = lane >> 4;
    const int c    = lane & 15;

    const int bid = (int)blockIdx.x;
    const int bh  = bid % 24;
    const int c2  = 79 - (bid / 24);    // long chunks first
    int qt, kc;
    if (c2 < 8)       { qt = c2;                    kc = 0; }
    else if (c2 < 24) { qt = 8 + ((c2 - 8) >> 1);   kc = (c2 - 8) & 1; }
    else if (c2 < 48) { qt = 16 + (c2 - 24) / 3;    kc = (c2 - 24) % 3; }
    else              { qt = 24 + ((c2 - 48) >> 2); kc = (c2 - 48) & 3; }
    const int qbase = qt * 64;

    const unsigned short* qrow = qg + (size_t)bh * SEQ * 64;
    const unsigned short* krow = kg + (size_t)bh * SEQ * 64;
    const unsigned short* vrow = vg + (size_t)bh * 64 * SEQ;

    // Q B-fragments (hoisted, direct from global): lane holds Q[q=c][d]
    const unsigned short* qp = qrow + (size_t)(qbase + w * 16 + c) * 64 + quad * 8;
    const v8s bq0 = *(const v8s*)(qp);
    const v8s bq1 = *(const v8s*)(qp + 32);

    // staging source pointers (chunk-swizzled)
    const int r0 = tid >> 3;
    const int ch0 = (tid & 7) ^ (r0 & 7);
    const unsigned short* kp0 = krow + (size_t)r0 * 64 + ch0 * 8;
    const unsigned short* vp0 = vrow + (size_t)r0 * SEQ + ch0 * 8;

    // fragment-read swizzled chunk offsets (ush)
    const int swz0 = ((quad ^ (c & 7)) * 8);
    const int swz1 = swz0 ^ 32;

    v4f oacc[4];
#pragma unroll
    for (int d = 0; d < 4; d++) oacc[d] = (v4f){0.f, 0.f, 0.f, 0.f};
    float l_acc = 0.f;

    const int q_lane = qbase + w * 16 + c;
    unsigned int* pw32 = (unsigned int*)&ps[w][0];
    const int psq = c & 7;

    const int kt0 = kc * 8;
    const int kt1 = min(kt0 + 8, qt + 1);

    // prologue: DMA tile kt0 into buf (kt0&1)
    {
        const int key0 = kt0 * 64;
        const int b = kt0 & 1;
        gload_lds16(kp0 + (size_t)key0 * 64, &ks[b][tid * 8]);
        gload_lds16(kp0 + (size_t)(key0 + 32) * 64, &ks[b][(256 + tid) * 8]);
        gload_lds16(vp0 + key0, &vs[b][tid * 8]);
        gload_lds16(vp0 + 32 * SEQ + key0, &vs[b][(256 + tid) * 8]);
    }

    for (int kt = kt0; kt < kt1; kt++) {
        const int b = kt & 1;
        __syncthreads();   // drains DMA(kt) into buf b; prev-tile reads done
        if (kt + 1 < kt1) {
            const int key0n = (kt + 1) * 64;
            gload_lds16(kp0 + (size_t)key0n * 64, &ks[b ^ 1][tid * 8]);
            gload_lds16(kp0 + (size_t)(key0n + 32) * 64, &ks[b ^ 1][(256 + tid) * 8]);
            gload_lds16(vp0 + key0n, &vs[b ^ 1][tid * 8]);
            gload_lds16(vp0 + 32 * SEQ + key0n, &vs[b ^ 1][(256 + tid) * 8]);
        }
        const int key0 = kt * 64;

        // ---- S^T = K Q^T ----
        v4f sacc[4];
#pragma unroll
        for (int n = 0; n < 4; n++) {
            const int rb = (n * 16 + c) * 64;
            const v8s ak0 = *(const v8s*)&ks[b][rb + swz0];
            const v8s ak1 = *(const v8s*)&ks[b][rb + swz1];
            v4f s = (v4f){0.f, 0.f, 0.f, 0.f};
            s = __builtin_amdgcn_mfma_f32_16x16x32_bf16(ak0, bq0, s, 0, 0, 0);
            s = __builtin_amdgcn_mfma_f32_16x16x32_bf16(ak1, bq1, s, 0, 0, 0);
            sacc[n] = s;   // elem r: key = key0+n*16+quad*4+r, query = q_lane
        }

        // ---- causal mask (diagonal tile only) ----
        if (kt == qt) {
            const int kb = key0 + quad * 4;
#pragma unroll
            for (int n = 0; n < 4; n++)
#pragma unroll
                for (int r = 0; r < 4; r++)
                    if (kb + n * 16 + r > q_lane) sacc[n][r] = -1e30f;
        }

        // ---- p = exp2(s), lane-local l, perm-pack -> ps (swizzled) ----
#pragma unroll
        for (int n = 0; n < 4; n++) {
            const float p0 = exp2f(sacc[n][0]);
            const float p1 = exp2f(sacc[n][1]);
            const float p2 = exp2f(sacc[n][2]);
            const float p3 = exp2f(sacc[n][3]);
            l_acc += (p0 + p1) + (p2 + p3);
            const int sswz = (2 * n + (quad >> 1)) ^ psq;
            const int dw = c * 32 + sswz * 4 + (quad & 1) * 2;
            pw32[dw]     = pack_bf16(p0, p1);
            pw32[dw + 1] = pack_bf16(p2, p3);
        }

        // ---- O += P V ----
        const v8s ap0 = *(const v8s*)&ps[w][c * 64 + swz0];
        const v8s ap1 = *(const v8s*)&ps[w][c * 64 + swz1];
#pragma unroll
        for (int d = 0; d < 4; d++) {
            const int rb = (d * 16 + c) * 64;
            const v8s bv0 = *(const v8s*)&vs[b][rb + swz0];
            const v8s bv1 = *(const v8s*)&vs[b][rb + swz1];
            oacc[d] = __builtin_amdgcn_mfma_f32_16x16x32_bf16(ap0, bv0, oacc[d], 0, 0, 0);
            oacc[d] = __builtin_amdgcn_mfma_f32_16x16x32_bf16(ap1, bv1, oacc[d], 0, 0, 0);
        }
    }

    // ---- l: reduce the 4 quad-partials for each q ----
    l_acc += __shfl_xor(l_acc, 16, 64);
    l_acc += __shfl_xor(l_acc, 32, 64);

    if (c2 < 8) {
        // ---- single-chunk row: normalize in-register, write y directly ----
        const int b = bh / N_HEAD;
        const int h = bh - b * N_HEAD;
#pragma unroll
        for (int r = 0; r < 4; r++) {
            const float inv = 1.0f / __shfl(l_acc, quad * 4 + r, 64);
            const int tq = qbase + w * 16 + quad * 4 + r;
            unsigned short* yr = y + ((size_t)(b * SEQ + tq)) * N_EMBD + h * 64;
#pragma unroll
            for (int d = 0; d < 4; d++)
                yr[d * 16 + c] = f2bf(oacc[d][r] * inv);
        }
        return;
    }

    // ---- write unnormalized partials ----
    const size_t pidx = (size_t)bh * 80 + c2;
    unsigned short* po = pO + pidx * 4096;
#pragma unroll
    for (int r = 0; r < 4; r++) {
        const int row = w * 16 + quad * 4 + r;
#pragma unroll
        for (int d = 0; d < 4; d++)
            po[row * 64 + d * 16 + c] = f2bf(oacc[d][r]);
    }
    if (lane < 16)
        pl[pidx * 64 + w * 16 + c] = l_acc;
}

// ---------------------------------------------------------------------------
// Kernel 2b: combine partials -> y bf16, only qt in [8,32).
// ---------------------------------------------------------------------------
__global__ __launch_bounds__(256) void combine_kernel(
    const unsigned short* __restrict__ pO,
    const float* __restrict__ pl,
    unsigned short* __restrict__ y)
{
    const int qt = 8 + (int)blockIdx.x;
    const int bh = (int)blockIdx.y;
    int base, nc;
    if (qt < 16)      { base = 8 + 2 * (qt - 8);   nc = 2; }
    else if (qt < 24) { base = 24 + 3 * (qt - 16); nc = 3; }
    else              { base = 48 + 4 * (qt - 24); nc = 4; }

    const int row = threadIdx.x >> 2;
    const int colg = (threadIdx.x & 3) * 16;

    float denom = 0.f;
    for (int i = 0; i < nc; i++)
        denom += pl[((size_t)bh * 80 + base + i) * 64 + row];
    const float inv = 1.0f / denom;

    float acc[16];
#pragma unroll
    for (int j = 0; j < 16; j++) acc[j] = 0.f;
    for (int i = 0; i < nc; i++) {
        const unsigned short* po = pO + ((size_t)bh * 80 + base + i) * 4096 + row * 64 + colg;
        ushort4 u0 = *(const ushort4*)(po + 0);
        ushort4 u1 = *(const ushort4*)(po + 4);
        ushort4 u2 = *(const ushort4*)(po + 8);
        ushort4 u3 = *(const ushort4*)(po + 12);
        acc[0]  += bf2f(u0.x); acc[1]  += bf2f(u0.y);
        acc[2]  += bf2f(u0.z); acc[3]  += bf2f(u0.w);
        acc[4]  += bf2f(u1.x); acc[5]  += bf2f(u1.y);
        acc[6]  += bf2f(u1.z); acc[7]  += bf2f(u1.w);
        acc[8]  += bf2f(u2.x); acc[9]  += bf2f(u2.y);
        acc[10] += bf2f(u2.z); acc[11] += bf2f(u2.w);
        acc[12] += bf2f(u3.x); acc[13] += bf2f(u3.y);
        acc[14] += bf2f(u3.z); acc[15] += bf2f(u3.w);
    }

    const int b = bh / N_HEAD;
    const int h = bh - b * N_HEAD;
    const int t = qt * 64 + row;
    unsigned short* yr = y + ((size_t)(b * SEQ + t)) * N_EMBD + h * 64 + colg;
    ushort4 o0, o1, o2, o3;
    o0.x = f2bf(acc[0] * inv);  o0.y = f2bf(acc[1] * inv);
    o0.z = f2bf(acc[2] * inv);  o0.w = f2bf(acc[3] * inv);
    o1.x = f2bf(acc[4] * inv);  o1.y = f2bf(acc[5] * inv);
    o1.z = f2bf(acc[6] * inv);  o1.w = f2bf(acc[7] * inv);
    o2.x = f2bf(acc[8] * inv);  o2.y = f2bf(acc[9] * inv);
    o2.z = f2bf(acc[10] * inv); o2.w = f2bf(acc[11] * inv);
    o3.x = f2bf(acc[12] * inv); o3.y = f2bf(acc[13] * inv);
    o3.z = f2bf(acc[14] * inv); o3.w = f2bf(acc[15] * inv);
    *(ushort4*)(yr + 0)  = o0;
    *(ushort4*)(yr + 4)  = o1;
    *(ushort4*)(yr + 8)  = o2;
    *(ushort4*)(yr + 12) = o3;
}

// ---------------------------------------------------------------------------
// Kernel 3: output projection, bf16 MFMA, 64x64 tile -> 768 blocks = 3/CU
// (was 192 = 0.75/CU: a third of the machine idle).  Double-buffered.
// ---------------------------------------------------------------------------
__global__ __launch_bounds__(256) void proj_gemm_mfma(
    const unsigned short* __restrict__ A,    // bf16 y [4096][768]
    const unsigned short* __restrict__ Bt,   // bf16 Wp^T [768][768]
    const float* __restrict__ bias,
    float* __restrict__ out)
{
    __shared__ unsigned short as[2][64 * 32];
    __shared__ unsigned short bs[2][64 * 32];
    const int K = 768;
    const int tid = threadIdx.x;
    const int lane = tid & 63;
    const int w = tid >> 6;
    const int wm = w >> 1, wn = w & 1;      // 2x2 wave grid over 64x64
    const int quad = lane >> 4, c = lane & 15;
    const int bm = blockIdx.y * 64;
    const int bn = blockIdx.x * 64;

    const int srow = tid >> 2;      // 0..63
    const int soff = (tid & 3) * 8;
    const unsigned short* ap = A  + (size_t)(bm + srow) * K + soff;
    const unsigned short* bp = Bt + (size_t)(bn + srow) * K + soff;

    v4f acc[2][2];
#pragma unroll
    for (int i = 0; i < 2; i++)
#pragma unroll
        for (int j = 0; j < 2; j++) acc[i][j] = (v4f){0.f, 0.f, 0.f, 0.f};

    gload_lds16(ap, &as[0][tid * 8]);
    gload_lds16(bp, &bs[0][tid * 8]);

    int bufi = 0;
    for (int k0 = 0; k0 < K; k0 += 32, bufi ^= 1) {
        __syncthreads();
        if (k0 + 32 < K) {
            const int kn = k0 + 32;
            gload_lds16(ap + kn, &as[bufi ^ 1][tid * 8]);
            gload_lds16(bp + kn, &bs[bufi ^ 1][tid * 8]);
        }

        v8s af[2], bf[2];
#pragma unroll
        for (int fm = 0; fm < 2; fm++)
            af[fm] = *(const v8s*)&as[bufi][(wm * 32 + fm * 16 + c) * 32 + quad * 8];
#pragma unroll
        for (int fn = 0; fn < 2; fn++)
            bf[fn] = *(const v8s*)&bs[bufi][(wn * 32 + fn * 16 + c) * 32 + quad * 8];
#pragma unroll
        for (int fm = 0; fm < 2; fm++)
#pragma unroll
            for (int fn = 0; fn < 2; fn++)
                acc[fm][fn] = __builtin_amdgcn_mfma_f32_16x16x32_bf16(af[fm], bf[fn], acc[fm][fn], 0, 0, 0);
    }

#pragma unroll
    for (int fm = 0; fm < 2; fm++) {
        const int m0 = bm + wm * 32 + fm * 16 + quad * 4;
#pragma unroll
        for (int fn = 0; fn < 2; fn++) {
            const int n = bn + wn * 32 + fn * 16 + c;
            const float bv = bias[n];
#pragma unroll
            for (int r = 0; r < 4; r++)
                out[(size_t)(m0 + r) * N_EMBD + n] = acc[fm][fn][r] + bv;
        }
    }
}

// ---------------------------------------------------------------------------
extern "C" void kernel_launch(void* const* d_in, const int* in_sizes, int n_in,
                              void* d_out, int out_size, void* d_ws, size_t ws_size,
                              hipStream_t stream) {
    const float* x      = (const float*)d_in[0];
    const float* W_attn = (const float*)d_in[1];
    const float* b_attn = (const float*)d_in[2];
    const float* W_proj = (const float*)d_in[3];
    const float* b_proj = (const float*)d_in[4];
    float* out = (float*)d_out;

    const size_t QSZ = (size_t)BATCH * N_HEAD * SEQ * HEAD_DIM;  // 3,145,728

    // ws layout: pO (15.7MB) aliases xb+wta (dead before attn runs);
    // then pl, wtp, qg, kg, vg, yb.  ~42 MB total.
    unsigned short* base = (unsigned short*)d_ws;
    unsigned short* xb  = base;                       // [4096][768]
    unsigned short* wta = base + QSZ;                 // [2304][768]
    unsigned short* pO  = base;                       // 1920*4096 ush (alias)
    float* pl = (float*)(base + (size_t)1920 * 4096); // 1920*64
    unsigned short* wtp = (unsigned short*)(pl + 1920 * 64);  // [768][768]
    unsigned short* qg  = wtp + (size_t)N_EMBD * N_EMBD;
    unsigned short* kg  = qg + QSZ;
    unsigned short* vg  = kg + QSZ;
    unsigned short* yb  = vg + QSZ;

    prep_kernel<<<dim3(3840), 256, 0, stream>>>(x, W_attn, W_proj, xb, wta, wtp);
    qkv_gemm_mfma<<<dim3(18, 32), 256, 0, stream>>>(xb, wta, b_attn, qg, kg, vg);
    attn_kernel<<<dim3(80 * 24), 256, 0, stream>>>(qg, kg, vg, pO, pl, yb);
    combine_kernel<<<dim3(24, BATCH * N_HEAD), 256, 0, stream>>>(pO, pl, yb);
    proj_gemm_mfma<<<dim3(12, 64), 256, 0, stream>>>(yb, wtp, b_proj, out);
}

// Round 13
// 160.884 us; speedup vs baseline: 1.0416x; 1.0416x over previous
//
#include <hip/hip_runtime.h>
#include <math.h>

#define N_EMBD 768
#define N_HEAD 12
#define HEAD_DIM 64
#define SEQ 2048
#define BATCH 2

typedef __attribute__((ext_vector_type(8))) short v8s;   // 8 bf16 (4 VGPRs)
typedef __attribute__((ext_vector_type(4))) float v4f;   // 4 fp32

__device__ __forceinline__ unsigned short f2bf(float f) {
    union { float f; unsigned int u; } x; x.f = f;
    unsigned int u = x.u + 0x7fffu + ((x.u >> 16) & 1u);
    return (unsigned short)(u >> 16);
}
__device__ __forceinline__ float bf2f(unsigned short s) {
    union { unsigned int u; float f; } x; x.u = ((unsigned int)s) << 16;
    return x.f;
}
// pack two fp32 -> packed bf16 pair (round-half-up via +0x8000, then byte-perm)
__device__ __forceinline__ unsigned int pack_bf16(float lo, float hi) {
    unsigned int ul = __float_as_uint(lo) + 0x8000u;
    unsigned int uh = __float_as_uint(hi) + 0x8000u;
    return __builtin_amdgcn_perm(uh, ul, 0x07060302);  // {hi[3],hi[2],lo[3],lo[2]}
}

__device__ __forceinline__ void gload_lds16(const unsigned short* g, unsigned short* l) {
    __builtin_amdgcn_global_load_lds(
        (const __attribute__((address_space(1))) void*)g,
        (__attribute__((address_space(3))) void*)l, 16, 0, 0);
}

// Q pre-scale: 1/sqrt(64) * log2(e)
#define QSCALE 0.1803368801111396f

// ---------------------------------------------------------------------------
// Prep: cast x -> bf16 (blocks [0,768), 16 elems/thread), transpose+cast
// W_attn (768..2496), transpose+cast W_proj (2496..3072).
// ---------------------------------------------------------------------------
__global__ __launch_bounds__(256) void prep_kernel(
    const float* __restrict__ x,
    const float* __restrict__ W_attn,
    const float* __restrict__ W_proj,
    unsigned short* __restrict__ xb,
    unsigned short* __restrict__ wta,
    unsigned short* __restrict__ wtp)
{
    __shared__ float t[32][33];
    const int blk = (int)blockIdx.x;
    if (blk < 768) {
        const int i = (blk * 256 + threadIdx.x) * 16;
#pragma unroll
        for (int p = 0; p < 4; p++) {
            const float4 a = *(const float4*)(x + i + p * 4);
            ushort4 s;
            s.x = f2bf(a.x); s.y = f2bf(a.y); s.z = f2bf(a.z); s.w = f2bf(a.w);
            *(ushort4*)(xb + i + p * 4) = s;
        }
        return;
    }
    const float* in; unsigned short* out; int R, C, bx, by;
    if (blk < 768 + 1728) {
        const int b2 = blk - 768;
        in = W_attn; out = wta; R = 768; C = 2304;
        bx = (b2 % 72) * 32; by = (b2 / 72) * 32;
    } else {
        const int b2 = blk - 2496;
        in = W_proj; out = wtp; R = 768; C = 768;
        bx = (b2 % 24) * 32; by = (b2 / 24) * 32;
    }
    const int tx = threadIdx.x & 31, ty = threadIdx.x >> 5;
#pragma unroll
    for (int i = 0; i < 32; i += 8)
        t[ty + i][tx] = in[(size_t)(by + ty + i) * C + bx + tx];
    __syncthreads();
#pragma unroll
    for (int i = 0; i < 32; i += 8)
        out[(size_t)(bx + ty + i) * R + by + tx] = f2bf(t[tx][ty + i]);
}

// ---------------------------------------------------------------------------
// Kernel 1: QKV GEMM, bf16 MFMA, 128x64 tile, BK=32, double-buffered
// (R11 config — best measured).  Wave tile 64x32 = 4x2 fragments.
// ---------------------------------------------------------------------------
__global__ __launch_bounds__(256) void qkv_gemm_mfma(
    const unsigned short* __restrict__ A,    // bf16 [4096][768]
    const unsigned short* __restrict__ Bt,   // bf16 [2304][768]
    const float* __restrict__ bias,
    unsigned short* __restrict__ qg,
    unsigned short* __restrict__ kg,
    unsigned short* __restrict__ vg)
{
    __shared__ unsigned short as[2][128 * 32];
    __shared__ unsigned short bs[2][64 * 32];
    const int K = 768;
    const int tid = threadIdx.x;
    const int lane = tid & 63;
    const int w = tid >> 6;
    const int wm = w >> 1, wn = w & 1;      // 2x2 wave grid over 128x64
    const int quad = lane >> 4, c = lane & 15;
    const int bm = blockIdx.y * 128;
    const int bn = blockIdx.x * 64;

    const int srow = tid >> 2;
    const int soff = (tid & 3) * 8;
    const unsigned short* ap  = A  + (size_t)(bm + srow) * K + soff;
    const unsigned short* ap2 = A  + (size_t)(bm + 64 + srow) * K + soff;
    const unsigned short* bp  = Bt + (size_t)(bn + srow) * K + soff;

    v4f acc[4][2];
#pragma unroll
    for (int i = 0; i < 4; i++)
#pragma unroll
        for (int j = 0; j < 2; j++) acc[i][j] = (v4f){0.f, 0.f, 0.f, 0.f};

    gload_lds16(ap,  &as[0][tid * 8]);
    gload_lds16(ap2, &as[0][(256 + tid) * 8]);
    gload_lds16(bp,  &bs[0][tid * 8]);

    int bufi = 0;
    for (int k0 = 0; k0 < K; k0 += 32, bufi ^= 1) {
        __syncthreads();
        if (k0 + 32 < K) {
            const int kn = k0 + 32;
            gload_lds16(ap + kn,  &as[bufi ^ 1][tid * 8]);
            gload_lds16(ap2 + kn, &as[bufi ^ 1][(256 + tid) * 8]);
            gload_lds16(bp + kn,  &bs[bufi ^ 1][tid * 8]);
        }

        v8s af[4], bf[2];
#pragma unroll
        for (int fm = 0; fm < 4; fm++)
            af[fm] = *(const v8s*)&as[bufi][(wm * 64 + fm * 16 + c) * 32 + quad * 8];
#pragma unroll
        for (int fn = 0; fn < 2; fn++)
            bf[fn] = *(const v8s*)&bs[bufi][(wn * 32 + fn * 16 + c) * 32 + quad * 8];
#pragma unroll
        for (int fm = 0; fm < 4; fm++)
#pragma unroll
            for (int fn = 0; fn < 2; fn++)
                acc[fm][fn] = __builtin_amdgcn_mfma_f32_16x16x32_bf16(af[fm], bf[fn], acc[fm][fn], 0, 0, 0);
    }

    // epilogue: 64-wide n-tile lies inside one of q/k/v AND one head
    const int which = bn / N_EMBD;           // 0=q 1=k 2=v
    const int h = (bn - which * N_EMBD) >> 6;
#pragma unroll
    for (int fm = 0; fm < 4; fm++) {
        const int m0 = bm + wm * 64 + fm * 16 + quad * 4;
        const int b = m0 >> 11;
        const int t0 = m0 & (SEQ - 1);
        const size_t bh = (size_t)(b * N_HEAD + h);
#pragma unroll
        for (int fn = 0; fn < 2; fn++) {
            const int d = wn * 32 + fn * 16 + c;
            const float bv = bias[bn + d];
            if (which == 2) {
                ushort4 o;
                o.x = f2bf(acc[fm][fn][0] + bv);
                o.y = f2bf(acc[fm][fn][1] + bv);
                o.z = f2bf(acc[fm][fn][2] + bv);
                o.w = f2bf(acc[fm][fn][3] + bv);
                *(ushort4*)(vg + (bh * 64 + d) * SEQ + t0) = o;
            } else {
                unsigned short* dst = (which == 0) ? qg : kg;
                const float sc = (which == 0) ? QSCALE : 1.0f;
#pragma unroll
                for (int r = 0; r < 4; r++)
                    dst[(bh * SEQ + t0 + r) * 64 + d] = f2bf((acc[fm][fn][r] + bv) * sc);
            }
        }
    }
}

// ---------------------------------------------------------------------------
// Kernel 2: causal flash attention (R8 structure: 64 q/block, 16 q/wave,
// split-K, fixed-max softmax, S^T operands, swizzled DMA staging, dbuf).
// Single-chunk rows (c2 < 8) normalize in-register and write y directly.
// ---------------------------------------------------------------------------
__global__ __launch_bounds__(256) void attn_kernel(
    const unsigned short* __restrict__ qg,
    const unsigned short* __restrict__ kg,
    const unsigned short* __restrict__ vg,
    unsigned short* __restrict__ pO,   // [bh*80+c2][64][64] bf16, unnormalized
    float* __restrict__ pl,            // [bh*80+c2][64] row sums
    unsigned short* __restrict__ y)    // bf16 [B,T,C] (direct path)
{
    __shared__ __align__(16) unsigned short ks[2][64 * 64];
    __shared__ __align__(16) unsigned short vs[2][64 * 64];
    __shared__ __align__(16) unsigned short ps[4][16 * 64];

    const int tid  = threadIdx.x;
    const int w    = tid >> 6;
    const int lane = tid & 63;
    const int quad = lane >> 4;
    const int c    = lane & 15;

    const int bid = (int)blockIdx.x;
    const int bh  = bid % 24;
    const int c2  = 79 - (bid / 24);    // long chunks first
    int qt, kc;
    if (c2 < 8)       { qt = c2;                    kc = 0; }
    else if (c2 < 24) { qt = 8 + ((c2 - 8) >> 1);   kc = (c2 - 8) & 1; }
    else if (c2 < 48) { qt = 16 + (c2 - 24) / 3;    kc = (c2 - 24) % 3; }
    else              { qt = 24 + ((c2 - 48) >> 2); kc = (c2 - 48) & 3; }
    const int qbase = qt * 64;

    const unsigned short* qrow = qg + (size_t)bh * SEQ * 64;
    const unsigned short* krow = kg + (size_t)bh * SEQ * 64;
    const unsigned short* vrow = vg + (size_t)bh * 64 * SEQ;

    // Q B-fragments (hoisted, direct from global): lane holds Q[q=c][d]
    const unsigned short* qp = qrow + (size_t)(qbase + w * 16 + c) * 64 + quad * 8;
    const v8s bq0 = *(const v8s*)(qp);
    const v8s bq1 = *(const v8s*)(qp + 32);

    // staging source pointers (chunk-swizzled)
    const int r0 = tid >> 3;
    const int ch0 = (tid & 7) ^ (r0 & 7);
    const unsigned short* kp0 = krow + (size_t)r0 * 64 + ch0 * 8;
    const unsigned short* vp0 = vrow + (size_t)r0 * SEQ + ch0 * 8;

    // fragment-read swizzled chunk offsets (ush)
    const int swz0 = ((quad ^ (c & 7)) * 8);
    const int swz1 = swz0 ^ 32;

    v4f oacc[4];
#pragma unroll
    for (int d = 0; d < 4; d++) oacc[d] = (v4f){0.f, 0.f, 0.f, 0.f};
    float l_acc = 0.f;

    const int q_lane = qbase + w * 16 + c;
    unsigned int* pw32 = (unsigned int*)&ps[w][0];
    const int psq = c & 7;

    const int kt0 = kc * 8;
    const int kt1 = min(kt0 + 8, qt + 1);

    // prologue: DMA tile kt0 into buf (kt0&1)
    {
        const int key0 = kt0 * 64;
        const int b = kt0 & 1;
        gload_lds16(kp0 + (size_t)key0 * 64, &ks[b][tid * 8]);
        gload_lds16(kp0 + (size_t)(key0 + 32) * 64, &ks[b][(256 + tid) * 8]);
        gload_lds16(vp0 + key0, &vs[b][tid * 8]);
        gload_lds16(vp0 + 32 * SEQ + key0, &vs[b][(256 + tid) * 8]);
    }

    for (int kt = kt0; kt < kt1; kt++) {
        const int b = kt & 1;
        __syncthreads();   // drains DMA(kt) into buf b; prev-tile reads done
        if (kt + 1 < kt1) {
            const int key0n = (kt + 1) * 64;
            gload_lds16(kp0 + (size_t)key0n * 64, &ks[b ^ 1][tid * 8]);
            gload_lds16(kp0 + (size_t)(key0n + 32) * 64, &ks[b ^ 1][(256 + tid) * 8]);
            gload_lds16(vp0 + key0n, &vs[b ^ 1][tid * 8]);
            gload_lds16(vp0 + 32 * SEQ + key0n, &vs[b ^ 1][(256 + tid) * 8]);
        }
        const int key0 = kt * 64;

        // ---- S^T = K Q^T ----
        v4f sacc[4];
#pragma unroll
        for (int n = 0; n < 4; n++) {
            const int rb = (n * 16 + c) * 64;
            const v8s ak0 = *(const v8s*)&ks[b][rb + swz0];
            const v8s ak1 = *(const v8s*)&ks[b][rb + swz1];
            v4f s = (v4f){0.f, 0.f, 0.f, 0.f};
            s = __builtin_amdgcn_mfma_f32_16x16x32_bf16(ak0, bq0, s, 0, 0, 0);
            s = __builtin_amdgcn_mfma_f32_16x16x32_bf16(ak1, bq1, s, 0, 0, 0);
            sacc[n] = s;   // elem r: key = key0+n*16+quad*4+r, query = q_lane
        }

        // ---- causal mask (diagonal tile only) ----
        if (kt == qt) {
            const int kb = key0 + quad * 4;
#pragma unroll
            for (int n = 0; n < 4; n++)
#pragma unroll
                for (int r = 0; r < 4; r++)
                    if (kb + n * 16 + r > q_lane) sacc[n][r] = -1e30f;
        }

        // ---- p = exp2(s), lane-local l, perm-pack -> ps (swizzled) ----
#pragma unroll
        for (int n = 0; n < 4; n++) {
            const float p0 = exp2f(sacc[n][0]);
            const float p1 = exp2f(sacc[n][1]);
            const float p2 = exp2f(sacc[n][2]);
            const float p3 = exp2f(sacc[n][3]);
            l_acc += (p0 + p1) + (p2 + p3);
            const int sswz = (2 * n + (quad >> 1)) ^ psq;
            const int dw = c * 32 + sswz * 4 + (quad & 1) * 2;
            pw32[dw]     = pack_bf16(p0, p1);
            pw32[dw + 1] = pack_bf16(p2, p3);
        }

        // ---- O += P V ----
        const v8s ap0 = *(const v8s*)&ps[w][c * 64 + swz0];
        const v8s ap1 = *(const v8s*)&ps[w][c * 64 + swz1];
#pragma unroll
        for (int d = 0; d < 4; d++) {
            const int rb = (d * 16 + c) * 64;
            const v8s bv0 = *(const v8s*)&vs[b][rb + swz0];
            const v8s bv1 = *(const v8s*)&vs[b][rb + swz1];
            oacc[d] = __builtin_amdgcn_mfma_f32_16x16x32_bf16(ap0, bv0, oacc[d], 0, 0, 0);
            oacc[d] = __builtin_amdgcn_mfma_f32_16x16x32_bf16(ap1, bv1, oacc[d], 0, 0, 0);
        }
    }

    // ---- l: reduce the 4 quad-partials for each q ----
    l_acc += __shfl_xor(l_acc, 16, 64);
    l_acc += __shfl_xor(l_acc, 32, 64);

    if (c2 < 8) {
        // ---- single-chunk row: normalize in-register, write y directly ----
        const int b = bh / N_HEAD;
        const int h = bh - b * N_HEAD;
#pragma unroll
        for (int r = 0; r < 4; r++) {
            const float inv = 1.0f / __shfl(l_acc, quad * 4 + r, 64);
            const int tq = qbase + w * 16 + quad * 4 + r;
            unsigned short* yr = y + ((size_t)(b * SEQ + tq)) * N_EMBD + h * 64;
#pragma unroll
            for (int d = 0; d < 4; d++)
                yr[d * 16 + c] = f2bf(oacc[d][r] * inv);
        }
        return;
    }

    // ---- write unnormalized partials ----
    const size_t pidx = (size_t)bh * 80 + c2;
    unsigned short* po = pO + pidx * 4096;
#pragma unroll
    for (int r = 0; r < 4; r++) {
        const int row = w * 16 + quad * 4 + r;
#pragma unroll
        for (int d = 0; d < 4; d++)
            po[row * 64 + d * 16 + c] = f2bf(oacc[d][r]);
    }
    if (lane < 16)
        pl[pidx * 64 + w * 16 + c] = l_acc;
}

// ---------------------------------------------------------------------------
// Kernel 2b: combine partials -> y bf16, only qt in [8,32).
// ---------------------------------------------------------------------------
__global__ __launch_bounds__(256) void combine_kernel(
    const unsigned short* __restrict__ pO,
    const float* __restrict__ pl,
    unsigned short* __restrict__ y)
{
    const int qt = 8 + (int)blockIdx.x;
    const int bh = (int)blockIdx.y;
    int base, nc;
    if (qt < 16)      { base = 8 + 2 * (qt - 8);   nc = 2; }
    else if (qt < 24) { base = 24 + 3 * (qt - 16); nc = 3; }
    else              { base = 48 + 4 * (qt - 24); nc = 4; }

    const int row = threadIdx.x >> 2;
    const int colg = (threadIdx.x & 3) * 16;

    float denom = 0.f;
    for (int i = 0; i < nc; i++)
        denom += pl[((size_t)bh * 80 + base + i) * 64 + row];
    const float inv = 1.0f / denom;

    float acc[16];
#pragma unroll
    for (int j = 0; j < 16; j++) acc[j] = 0.f;
    for (int i = 0; i < nc; i++) {
        const unsigned short* po = pO + ((size_t)bh * 80 + base + i) * 4096 + row * 64 + colg;
        ushort4 u0 = *(const ushort4*)(po + 0);
        ushort4 u1 = *(const ushort4*)(po + 4);
        ushort4 u2 = *(const ushort4*)(po + 8);
        ushort4 u3 = *(const ushort4*)(po + 12);
        acc[0]  += bf2f(u0.x); acc[1]  += bf2f(u0.y);
        acc[2]  += bf2f(u0.z); acc[3]  += bf2f(u0.w);
        acc[4]  += bf2f(u1.x); acc[5]  += bf2f(u1.y);
        acc[6]  += bf2f(u1.z); acc[7]  += bf2f(u1.w);
        acc[8]  += bf2f(u2.x); acc[9]  += bf2f(u2.y);
        acc[10] += bf2f(u2.z); acc[11] += bf2f(u2.w);
        acc[12] += bf2f(u3.x); acc[13] += bf2f(u3.y);
        acc[14] += bf2f(u3.z); acc[15] += bf2f(u3.w);
    }

    const int b = bh / N_HEAD;
    const int h = bh - b * N_HEAD;
    const int t = qt * 64 + row;
    unsigned short* yr = y + ((size_t)(b * SEQ + t)) * N_EMBD + h * 64 + colg;
    ushort4 o0, o1, o2, o3;
    o0.x = f2bf(acc[0] * inv);  o0.y = f2bf(acc[1] * inv);
    o0.z = f2bf(acc[2] * inv);  o0.w = f2bf(acc[3] * inv);
    o1.x = f2bf(acc[4] * inv);  o1.y = f2bf(acc[5] * inv);
    o1.z = f2bf(acc[6] * inv);  o1.w = f2bf(acc[7] * inv);
    o2.x = f2bf(acc[8] * inv);  o2.y = f2bf(acc[9] * inv);
    o2.z = f2bf(acc[10] * inv); o2.w = f2bf(acc[11] * inv);
    o3.x = f2bf(acc[12] * inv); o3.y = f2bf(acc[13] * inv);
    o3.z = f2bf(acc[14] * inv); o3.w = f2bf(acc[15] * inv);
    *(ushort4*)(yr + 0)  = o0;
    *(ushort4*)(yr + 4)  = o1;
    *(ushort4*)(yr + 8)  = o2;
    *(ushort4*)(yr + 12) = o3;
}

// ---------------------------------------------------------------------------
// Kernel 3: output projection, bf16 MFMA, 128x128, double-buffered (R8/R11).
// ---------------------------------------------------------------------------
__global__ __launch_bounds__(256) void proj_gemm_mfma(
    const unsigned short* __restrict__ A,
    const unsigned short* __restrict__ Bt,
    const float* __restrict__ bias,
    float* __restrict__ out)
{
    __shared__ unsigned short as[2][128 * 32];
    __shared__ unsigned short bs[2][128 * 32];
    const int K = 768;
    const int tid = threadIdx.x;
    const int lane = tid & 63;
    const int w = tid >> 6;
    const int wm = w >> 1, wn = w & 1;
    const int quad = lane >> 4, c = lane & 15;
    const int bm = blockIdx.y * 128;
    const int bn = blockIdx.x * 128;

    const int srow = tid >> 2;
    const int soff = (tid & 3) * 8;
    const unsigned short* ap = A  + (size_t)(bm + srow) * K + soff;
    const unsigned short* bp = Bt + (size_t)(bn + srow) * K + soff;
    const unsigned short* ap2 = A  + (size_t)(bm + 64 + srow) * K + soff;
    const unsigned short* bp2 = Bt + (size_t)(bn + 64 + srow) * K + soff;

    v4f acc[4][4];
#pragma unroll
    for (int i = 0; i < 4; i++)
#pragma unroll
        for (int j = 0; j < 4; j++) acc[i][j] = (v4f){0.f, 0.f, 0.f, 0.f};

    gload_lds16(ap, &as[0][tid * 8]);
    gload_lds16(ap2, &as[0][(256 + tid) * 8]);
    gload_lds16(bp, &bs[0][tid * 8]);
    gload_lds16(bp2, &bs[0][(256 + tid) * 8]);

    int bufi = 0;
    for (int k0 = 0; k0 < K; k0 += 32, bufi ^= 1) {
        __syncthreads();
        if (k0 + 32 < K) {
            const int kn = k0 + 32;
            gload_lds16(ap + kn, &as[bufi ^ 1][tid * 8]);
            gload_lds16(ap2 + kn, &as[bufi ^ 1][(256 + tid) * 8]);
            gload_lds16(bp + kn, &bs[bufi ^ 1][tid * 8]);
            gload_lds16(bp2 + kn, &bs[bufi ^ 1][(256 + tid) * 8]);
        }

        v8s af[4], bf[4];
#pragma unroll
        for (int fm = 0; fm < 4; fm++)
            af[fm] = *(const v8s*)&as[bufi][(wm * 64 + fm * 16 + c) * 32 + quad * 8];
#pragma unroll
        for (int fn = 0; fn < 4; fn++)
            bf[fn] = *(const v8s*)&bs[bufi][(wn * 64 + fn * 16 + c) * 32 + quad * 8];
#pragma unroll
        for (int fm = 0; fm < 4; fm++)
#pragma unroll
            for (int fn = 0; fn < 4; fn++)
                acc[fm][fn] = __builtin_amdgcn_mfma_f32_16x16x32_bf16(af[fm], bf[fn], acc[fm][fn], 0, 0, 0);
    }

#pragma unroll
    for (int fm = 0; fm < 4; fm++) {
        const int m0 = bm + wm * 64 + fm * 16 + quad * 4;
#pragma unroll
        for (int fn = 0; fn < 4; fn++) {
            const int n = bn + wn * 64 + fn * 16 + c;
            const float bv = bias[n];
#pragma unroll
            for (int r = 0; r < 4; r++)
                out[(size_t)(m0 + r) * N_EMBD + n] = acc[fm][fn][r] + bv;
        }
    }
}

// ---------------------------------------------------------------------------
extern "C" void kernel_launch(void* const* d_in, const int* in_sizes, int n_in,
                              void* d_out, int out_size, void* d_ws, size_t ws_size,
                              hipStream_t stream) {
    const float* x      = (const float*)d_in[0];
    const float* W_attn = (const float*)d_in[1];
    const float* b_attn = (const float*)d_in[2];
    const float* W_proj = (const float*)d_in[3];
    const float* b_proj = (const float*)d_in[4];
    float* out = (float*)d_out;

    const size_t QSZ = (size_t)BATCH * N_HEAD * SEQ * HEAD_DIM;  // 3,145,728

    // ws layout: pO (15.7MB) aliases xb+wta (dead before attn runs);
    // then pl, wtp, qg, kg, vg, yb.  ~42 MB total.
    unsigned short* base = (unsigned short*)d_ws;
    unsigned short* xb  = base;                       // [4096][768]
    unsigned short* wta = base + QSZ;                 // [2304][768]
    unsigned short* pO  = base;                       // 1920*4096 ush (alias)
    float* pl = (float*)(base + (size_t)1920 * 4096); // 1920*64
    unsigned short* wtp = (unsigned short*)(pl + 1920 * 64);  // [768][768]
    unsigned short* qg  = wtp + (size_t)N_EMBD * N_EMBD;
    unsigned short* kg  = qg + QSZ;
    unsigned short* vg  = kg + QSZ;
    unsigned short* yb  = vg + QSZ;

    prep_kernel<<<dim3(3072), 256, 0, stream>>>(x, W_attn, W_proj, xb, wta, wtp);
    qkv_gemm_mfma<<<dim3(36, 32), 256, 0, stream>>>(xb, wta, b_attn, qg, kg, vg);
    attn_kernel<<<dim3(80 * 24), 256, 0, stream>>>(qg, kg, vg, pO, pl, yb);
    combine_kernel<<<dim3(24, BATCH * N_HEAD), 256, 0, stream>>>(pO, pl, yb);
    proj_gemm_mfma<<<dim3(6, 32), 256, 0, stream>>>(yb, wtp, b_proj, out);
}